// Round 1
// baseline (16127.676 us; speedup 1.0000x reference)
//
#include <hip/hip_runtime.h>
#include <hip/hip_bf16.h>

#define T_STEPS 256
#define BATCH   64
#define HID     512
#define NWG     256   // 4 batch-groups x 64 unit-groups
#define NTHR    256   // 4 waves

typedef float f32x4 __attribute__((ext_vector_type(4)));
typedef short bf16x8 __attribute__((ext_vector_type(8)));

// LDS layout (dynamic shared, 148992 B total -> 1 WG/CU)
#define W0OFF   0u        // [32][1024] bf16, swizzled   (layer0: rows = [i f g o] x 8 units, cols = [ih | hh])
#define W1OFF   65536u    // [32][1024] bf16, swizzled   (layer1)
#define WSTOFF  131072u   // [16][512] bf16, swizzled    (w_t rows; rows 8..15 zero)
#define T1OFF   147456u   // [16][16] f32 tile exchange (wave1 -> wave0)
#define BNCOFF  148480u   // [16][8]  f32 bounce (cell lanes -> row writers)
#define SMEM_BYTES 148992

__device__ __forceinline__ short f2b(float f) {
  __hip_bfloat16 h = __float2bfloat16(f);
  return *reinterpret_cast<short*>(&h);
}
__device__ __forceinline__ float b2f(short s) {
  __hip_bfloat16 h;
  *reinterpret_cast<short*>(&h) = s;
  return __bfloat162float(h);
}
__device__ __forceinline__ float sigf(float x) { return 1.0f / (1.0f + __expf(-x)); }
__device__ __forceinline__ float tanh_f(float x) { return 2.0f / (1.0f + __expf(-2.0f * x)) - 1.0f; }

__device__ __forceinline__ bf16x8 pack8(float4 a, float4 b) {
  bf16x8 r;
  r[0] = f2b(a.x); r[1] = f2b(a.y); r[2] = f2b(a.z); r[3] = f2b(a.w);
  r[4] = f2b(b.x); r[5] = f2b(b.y); r[6] = f2b(b.z); r[7] = f2b(b.w);
  return r;
}

// poll a 32-slot counter group until every slot reaches 8 (256 WGs / 32 slots)
__device__ __forceinline__ void spin_group(unsigned int* g) {
  const int lane = threadIdx.x & 63;
  unsigned int* p = g + (lane & 31);
  for (;;) {
    unsigned int v = __hip_atomic_load(p, __ATOMIC_RELAXED, __HIP_MEMORY_SCOPE_AGENT);
    unsigned long long b = __ballot(v >= 8u);
    if ((b & 0xFFFFFFFFull) == 0xFFFFFFFFull) break;
    __builtin_amdgcn_s_sleep(2);
  }
}

// stage one layer's gate-row slice (32 rows x 1024 K) fp32 global -> bf16 LDS, XOR-swizzled
__device__ __forceinline__ void stage_weights(char* smem, unsigned int base,
                                              const float* Wih, const float* Whh,
                                              int u0, int tid) {
  for (int p = tid; p < 4096; p += NTHR) {
    const int row = p >> 7;            // 0..31  (0-7 i, 8-15 f, 16-23 g, 24-31 o)
    const int col = (p & 127) * 8;     // 0..1016
    const int gate = row >> 3;
    const int grow = gate * 512 + u0 + (row & 7);
    const float* src = (col < 512) ? (Wih + (size_t)grow * HID + col)
                                   : (Whh + (size_t)grow * HID + (col - 512));
    float4 v0 = *(const float4*)src;
    float4 v1 = *(const float4*)(src + 4);
    unsigned int byte = base + (unsigned int)row * 2048u + (unsigned int)col * 2u;
    byte ^= (unsigned int)(row & 7) << 4;
    *(bf16x8*)(smem + byte) = pack8(v0, v1);
  }
}

// gates[16 x 16-tile] = A[16,512](aA) @ W[:, :512]^T + A[16,512](aB) @ W[:, 512:]^T
__device__ __forceinline__ f32x4 gates_mm(char* smem, const unsigned short* aA,
                                          const unsigned short* aB, unsigned int wOff,
                                          int tile, int bg, int lane) {
  f32x4 acc = {0.f, 0.f, 0.f, 0.f};
  const int arow = bg * 16 + (lane & 15);
  const int koff = (lane >> 4) * 8;
  const int brow = tile * 16 + (lane & 15);
  const unsigned int bb = wOff + (unsigned int)brow * 2048u;
  const unsigned int sw = (unsigned int)(brow & 7) << 4;
  const unsigned short* pa = aA + (size_t)arow * HID + koff;
#pragma unroll
  for (int ks = 0; ks < 16; ++ks) {
    bf16x8 a = *(const bf16x8*)(pa + ks * 32);
    bf16x8 b = *(const bf16x8*)(smem + ((bb + (unsigned int)((ks * 32 + koff) * 2)) ^ sw));
    acc = __builtin_amdgcn_mfma_f32_16x16x32_bf16(a, b, acc, 0, 0, 0);
  }
  const unsigned short* pb = aB + (size_t)arow * HID + koff;
#pragma unroll
  for (int ks = 0; ks < 16; ++ks) {
    bf16x8 a = *(const bf16x8*)(pb + ks * 32);
    bf16x8 b = *(const bf16x8*)(smem + ((bb + (unsigned int)((512 + ks * 32 + koff) * 2)) ^ sw));
    acc = __builtin_amdgcn_mfma_f32_16x16x32_bf16(a, b, acc, 0, 0, 0);
  }
  return acc;
}

// wave0: acc = tile0 [i|f]; T1 in LDS = tile1 [g|o]; produces h (hv) and updates c (cst)
__device__ __forceinline__ void cell_update(char* smem, f32x4 acc, float bt0, float bgb,
                                            float bob, float* cst, float* hv, int lane) {
#pragma unroll
  for (int j = 0; j < 4; ++j) acc[j] += bt0;   // own-column bias (i or f)
  float part[4];
#pragma unroll
  for (int j = 0; j < 4; ++j) part[j] = __shfl_xor(acc[j], 8);
  const float* T1 = (const float*)(smem + T1OFF);
  const int cs = lane & 7;
  const int rb = (lane >> 4) * 4;
#pragma unroll
  for (int j = 0; j < 4; ++j) {
    const float iv = acc[j];                       // valid for lanes col<8
    const float fv = part[j];
    const float gv = T1[(rb + j) * 16 + cs] + bgb;
    const float ov = T1[(rb + j) * 16 + cs + 8] + bob;
    const float cn = sigf(fv) * cst[j] + sigf(iv) * tanh_f(gv);
    cst[j] = cn;
    hv[j] = sigf(ov) * tanh_f(cn);
  }
}

extern "C" __global__ void __launch_bounds__(NTHR, 1)
dlstm_kernel(const float* __restrict__ init_h, const float* __restrict__ init_c,
             const float* __restrict__ eps_w, const float* __restrict__ eps_b,
             const float* __restrict__ W_ih0, const float* __restrict__ W_hh0,
             const float* __restrict__ b_ih0, const float* __restrict__ b_hh0,
             const float* __restrict__ W_ih1, const float* __restrict__ W_hh1,
             const float* __restrict__ b_ih1, const float* __restrict__ b_hh1,
             const float* __restrict__ w_mu, const float* __restrict__ w_log_var,
             const float* __restrict__ b_mu, const float* __restrict__ b_log_var,
             float* __restrict__ out, unsigned int* __restrict__ counters,
             unsigned short* __restrict__ xbuf, unsigned short* __restrict__ h0buf,
             unsigned short* __restrict__ h1buf) {
  extern __shared__ char smem[];
  const int tid = threadIdx.x;
  const int bid = blockIdx.x;
  const int bg = bid & 3;            // batch group: rows [bg*16, bg*16+16)
  const int u0 = (bid >> 2) * 8;     // unit slice: [u0, u0+8) per layer
  const int wave = tid >> 6;
  const int lane = tid & 63;
  const int col = lane & 15;
  const int cs = lane & 7;
  const int rb = (lane >> 4) * 4;
  const int slot = bid >> 3;         // 32 counter slots, 8 WGs each
  const bool is_act = col < 8;
  const size_t BH = (size_t)BATCH * HID;

  // ---------------- one-time init ----------------
  stage_weights(smem, W0OFF, W_ih0, W_hh0, u0, tid);
  stage_weights(smem, W1OFF, W_ih1, W_hh1, u0, tid);
  {  // zero wstage pad rows 8..15 (MFMA N-tile is 16 wide, only 8 real rows)
    bf16x8 z = {0, 0, 0, 0, 0, 0, 0, 0};
    for (int p = tid; p < 512; p += NTHR) {
      const int row = 8 + (p >> 6);
      const int c8 = (p & 63) * 8;
      unsigned int byte = WSTOFF + (unsigned int)row * 1024u + (unsigned int)c8 * 2u;
      byte ^= (unsigned int)(row & 7) << 4;
      *(bf16x8*)(smem + byte) = z;
    }
  }
  // per-thread BL slice: row erow of w_t slice, 16 cols at ecb
  const int erow = tid >> 5;
  const int ecb = (tid & 31) * 16;
  float mu_r[16], sg_r[16], ewr[16];
  {
    const float* pm = w_mu + (size_t)(u0 + erow) * HID + ecb;
    const float* pv = w_log_var + (size_t)(u0 + erow) * HID + ecb;
#pragma unroll
    for (int q = 0; q < 16; ++q) { mu_r[q] = pm[q]; sg_r[q] = __expf(0.5f * pv[q]); }
    const float* pe = eps_w + (size_t)(u0 + erow) * HID + ecb;  // t = 0
#pragma unroll
    for (int q = 0; q < 16; ++q) ewr[q] = pe[q];
  }
  // wave0 per-lane constants + states
  float bt0_l0 = 0, bt0_l1 = 0, bgb0 = 0, bob0 = 0, bgb1 = 0, bob1 = 0, bmu_l = 0, bsg_l = 0;
  float c0r[4] = {0, 0, 0, 0}, c1r[4] = {0, 0, 0, 0};
  if (wave == 0) {
    const int ofs = (col < 8) ? 0 : 512;
    const int un = u0 + cs;
    bt0_l0 = b_ih0[ofs + un] + b_hh0[ofs + un];
    bt0_l1 = b_ih1[ofs + un] + b_hh1[ofs + un];
    bgb0 = b_ih0[1024 + un] + b_hh0[1024 + un];
    bob0 = b_ih0[1536 + un] + b_hh0[1536 + un];
    bgb1 = b_ih1[1024 + un] + b_hh1[1024 + un];
    bob1 = b_ih1[1536 + un] + b_hh1[1536 + un];
    bmu_l = b_mu[un];
    bsg_l = __expf(0.5f * b_log_var[un]);
    if (is_act) {
#pragma unroll
      for (int j = 0; j < 4; ++j) {
        c0r[j] = init_c[(size_t)(0 * BATCH + bg * 16 + rb + j) * HID + un];
        c1r[j] = init_c[(size_t)(1 * BATCH + bg * 16 + rb + j) * HID + un];
      }
    }
    if (lane < 16) {  // write this WG's tile of the parity-0 state buffers
      const int row = bg * 16 + lane;
      const float* s0 = init_h + (size_t)row * HID + u0;
      const float* s1 = init_h + (size_t)(BATCH + row) * HID + u0;
      *(bf16x8*)(h0buf + (size_t)row * HID + u0) = pack8(*(const float4*)s0, *(const float4*)(s0 + 4));
      *(bf16x8*)(h1buf + (size_t)row * HID + u0) = pack8(*(const float4*)s1, *(const float4*)(s1 + 4));
      bf16x8 z = {0, 0, 0, 0, 0, 0, 0, 0};
      *(bf16x8*)(xbuf + (size_t)row * HID + u0) = z;  // x_0 = 0
    }
  }
  __syncthreads();
  if (wave == 0) {
    __builtin_amdgcn_fence(__ATOMIC_RELEASE, "agent");
    if (lane == 0)
      __hip_atomic_fetch_add(counters + slot, 1u, __ATOMIC_RELAXED, __HIP_MEMORY_SCOPE_AGENT);
  }

  // ---------------- time loop ----------------
#pragma unroll 1
  for (int t = 0; t < T_STEPS; ++t) {
    const int pp = t & 1;

    // build w_t slice into LDS (independent of recurrence; eps prefetched last iter)
    {
      bf16x8 v0, v1;
#pragma unroll
      for (int q = 0; q < 8; ++q) v0[q] = f2b(fmaf(sg_r[q], ewr[q], mu_r[q]));
#pragma unroll
      for (int q = 0; q < 8; ++q) v1[q] = f2b(fmaf(sg_r[q + 8], ewr[q + 8], mu_r[q + 8]));
      const unsigned int b0 = WSTOFF + (unsigned int)erow * 1024u + (unsigned int)ecb * 2u;
      const unsigned int sw = (unsigned int)(erow & 7) << 4;
      *(bf16x8*)(smem + (b0 ^ sw)) = v0;
      *(bf16x8*)(smem + ((b0 + 16u) ^ sw)) = v1;
    }
    if (t + 1 < T_STEPS) {  // prefetch eps_w[t+1]
      const float* pe = eps_w + (size_t)(t + 1) * HID * HID + (size_t)(u0 + erow) * HID + ecb;
#pragma unroll
      for (int q = 0; q < 16; ++q) ewr[q] = pe[q];
    }

    // ============== PHASE 0: gates0 -> h0 ==============
    if (wave == 0) spin_group(counters + 32 * (3 * t));  // t==0 -> init group
    __syncthreads();
    __builtin_amdgcn_fence(__ATOMIC_ACQUIRE, "agent");
    f32x4 acc = {0.f, 0.f, 0.f, 0.f};
    if (wave < 2) {
      acc = gates_mm(smem, xbuf + pp * BH, h0buf + pp * BH, W0OFF, wave, bg, lane);
      if (wave == 1) {
        float* T1 = (float*)(smem + T1OFF);
#pragma unroll
        for (int j = 0; j < 4; ++j) T1[(rb + j) * 16 + col] = acc[j];
      }
    }
    __syncthreads();
    if (wave == 0) {
      float hv[4];
      cell_update(smem, acc, bt0_l0, bgb0, bob0, c0r, hv, lane);
      float* BNC = (float*)(smem + BNCOFF);
      if (is_act) {
#pragma unroll
        for (int j = 0; j < 4; ++j) BNC[(rb + j) * 8 + cs] = hv[j];
      }
      asm volatile("s_waitcnt lgkmcnt(0)" ::: "memory");
      if (lane < 16) {
        const int row = bg * 16 + lane;
        float4 v0 = *(float4*)(BNC + lane * 8);
        float4 v1 = *(float4*)(BNC + lane * 8 + 4);
        *(bf16x8*)(h0buf + (size_t)(pp ^ 1) * BH + (size_t)row * HID + u0) = pack8(v0, v1);
      }
      __builtin_amdgcn_fence(__ATOMIC_RELEASE, "agent");
      if (lane == 0)
        __hip_atomic_fetch_add(counters + 32 * (1 + 3 * t) + slot, 1u, __ATOMIC_RELAXED,
                               __HIP_MEMORY_SCOPE_AGENT);
    }

    // ============== PHASE 1: gates1 -> h1 (+ d_out) ==============
    float ebv = 0.0f;
    if (wave == 0 && is_act) ebv = eps_b[(size_t)t * HID + u0 + cs];
    if (wave == 0) spin_group(counters + 32 * (1 + 3 * t));
    __syncthreads();
    __builtin_amdgcn_fence(__ATOMIC_ACQUIRE, "agent");
    if (wave < 2) {
      acc = gates_mm(smem, h0buf + (size_t)(pp ^ 1) * BH, h1buf + (size_t)pp * 2 * BH, W1OFF,
                     wave, bg, lane);
      if (wave == 1) {
        float* T1 = (float*)(smem + T1OFF);
#pragma unroll
        for (int j = 0; j < 4; ++j) T1[(rb + j) * 16 + col] = acc[j];
      }
    }
    __syncthreads();
    if (wave == 0) {
      float hv[4];
      cell_update(smem, acc, bt0_l1, bgb1, bob1, c1r, hv, lane);
      float* BNC = (float*)(smem + BNCOFF);
      if (is_act) {
#pragma unroll
        for (int j = 0; j < 4; ++j) BNC[(rb + j) * 8 + cs] = hv[j];
      }
      asm volatile("s_waitcnt lgkmcnt(0)" ::: "memory");
      if (lane < 16) {
        const int row = bg * 16 + lane;
        float4 v0 = *(float4*)(BNC + lane * 8);
        float4 v1 = *(float4*)(BNC + lane * 8 + 4);
        bf16x8 hi = pack8(v0, v1);
        unsigned short* base = h1buf + (size_t)(pp ^ 1) * 2 * BH;
        *(bf16x8*)(base + (size_t)row * HID + u0) = hi;
        bf16x8 lo;  // residual for the BL matmul (w_t row norms ~5.4 amplify h1 error)
        const float* va = (const float*)&v0;
        const float* vb = (const float*)&v1;
#pragma unroll
        for (int q = 0; q < 8; ++q) {
          const float f = (q < 4) ? va[q] : vb[q - 4];
          lo[q] = f2b(f - b2f(hi[q]));
        }
        *(bf16x8*)(base + BH + (size_t)row * HID + u0) = lo;
        float* od = out + ((size_t)t * BATCH + row) * HID + u0;
        *(float4*)od = v0;
        *(float4*)(od + 4) = v1;
      }
      __builtin_amdgcn_fence(__ATOMIC_RELEASE, "agent");
      if (lane == 0)
        __hip_atomic_fetch_add(counters + 32 * (2 + 3 * t) + slot, 1u, __ATOMIC_RELAXED,
                               __HIP_MEMORY_SCOPE_AGENT);
    }

    // ============== PHASE 2: x_{t+1} = h1 @ w_t^T + b_t ==============
    if (t + 1 < T_STEPS) {
      if (wave == 0) spin_group(counters + 32 * (2 + 3 * t));
      __syncthreads();
      __builtin_amdgcn_fence(__ATOMIC_ACQUIRE, "agent");
      if (wave == 0) {
        f32x4 a2 = {0.f, 0.f, 0.f, 0.f};
        const unsigned short* hh = h1buf + (size_t)(pp ^ 1) * 2 * BH;
        const int arow = bg * 16 + col;
        const int koff = (lane >> 4) * 8;
        const unsigned int bb = WSTOFF + (unsigned int)col * 1024u;
        const unsigned int sw = (unsigned int)(col & 7) << 4;
#pragma unroll
        for (int part = 0; part < 2; ++part) {  // hi then lo residual
          const unsigned short* pa = hh + (size_t)part * BH + (size_t)arow * HID + koff;
#pragma unroll
          for (int ks = 0; ks < 16; ++ks) {
            bf16x8 a = *(const bf16x8*)(pa + ks * 32);
            bf16x8 b =
                *(const bf16x8*)(smem + ((bb + (unsigned int)((ks * 32 + koff) * 2)) ^ sw));
            a2 = __builtin_amdgcn_mfma_f32_16x16x32_bf16(a, b, a2, 0, 0, 0);
          }
        }
        const float xb = bmu_l + bsg_l * ebv;
        float* BNC = (float*)(smem + BNCOFF);
        if (is_act) {
#pragma unroll
          for (int j = 0; j < 4; ++j) BNC[(rb + j) * 8 + cs] = a2[j] + xb;
        }
        asm volatile("s_waitcnt lgkmcnt(0)" ::: "memory");
        if (lane < 16) {
          const int row = bg * 16 + lane;
          float4 v0 = *(float4*)(BNC + lane * 8);
          float4 v1 = *(float4*)(BNC + lane * 8 + 4);
          *(bf16x8*)(xbuf + (size_t)(pp ^ 1) * BH + (size_t)row * HID + u0) = pack8(v0, v1);
        }
        __builtin_amdgcn_fence(__ATOMIC_RELEASE, "agent");
        if (lane == 0)
          __hip_atomic_fetch_add(counters + 32 * (3 + 3 * t) + slot, 1u, __ATOMIC_RELAXED,
                                 __HIP_MEMORY_SCOPE_AGENT);
      }
      __syncthreads();  // protect wstage rebuild at next loop top
    }
  }
}

extern "C" void kernel_launch(void* const* d_in, const int* in_sizes, int n_in, void* d_out,
                              int out_size, void* d_ws, size_t ws_size, hipStream_t stream) {
  const float* init_h = (const float*)d_in[1];
  const float* init_c = (const float*)d_in[2];
  const float* eps_w = (const float*)d_in[3];
  const float* eps_b = (const float*)d_in[4];
  const float* W_ih0 = (const float*)d_in[5];
  const float* W_hh0 = (const float*)d_in[6];
  const float* b_ih0 = (const float*)d_in[7];
  const float* b_hh0 = (const float*)d_in[8];
  const float* W_ih1 = (const float*)d_in[9];
  const float* W_hh1 = (const float*)d_in[10];
  const float* b_ih1 = (const float*)d_in[11];
  const float* b_hh1 = (const float*)d_in[12];
  const float* w_mu = (const float*)d_in[13];
  const float* w_log_var = (const float*)d_in[14];
  const float* b_mu = (const float*)d_in[15];
  const float* b_log_var = (const float*)d_in[16];
  float* out = (float*)d_out;

  unsigned char* ws = (unsigned char*)d_ws;
  unsigned int* counters = (unsigned int*)ws;                       // 769 groups * 32 * 4B
  unsigned short* xbuf = (unsigned short*)(ws + 131072);            // 2 parity * 64*512 bf16
  unsigned short* h0buf = (unsigned short*)(ws + 262144);           // 2 parity
  unsigned short* h1buf = (unsigned short*)(ws + 393216);           // 2 parity * {hi,lo}

  hipMemsetAsync(counters, 0, (1 + 3 * T_STEPS) * 32 * sizeof(unsigned int), stream);
  hipFuncSetAttribute((const void*)dlstm_kernel, hipFuncAttributeMaxDynamicSharedMemorySize,
                      SMEM_BYTES);

  void* args[] = {(void*)&init_h, (void*)&init_c, (void*)&eps_w,  (void*)&eps_b,
                  (void*)&W_ih0,  (void*)&W_hh0,  (void*)&b_ih0,  (void*)&b_hh0,
                  (void*)&W_ih1,  (void*)&W_hh1,  (void*)&b_ih1,  (void*)&b_hh1,
                  (void*)&w_mu,   (void*)&w_log_var, (void*)&b_mu, (void*)&b_log_var,
                  (void*)&out,    (void*)&counters,  (void*)&xbuf, (void*)&h0buf,
                  (void*)&h1buf};
  hipError_t err = hipLaunchCooperativeKernel((void*)dlstm_kernel, dim3(NWG), dim3(NTHR), args,
                                              SMEM_BYTES, stream);
  if (err != hipSuccess) {
    // fallback: plain launch (256 WGs at 1/CU on 256 CUs are co-resident by capacity)
    hipLaunchKernelGGL(dlstm_kernel, dim3(NWG), dim3(NTHR), SMEM_BYTES, stream, init_h, init_c,
                       eps_w, eps_b, W_ih0, W_hh0, b_ih0, b_hh0, W_ih1, W_hh1, b_ih1, b_hh1,
                       w_mu, w_log_var, b_mu, b_log_var, out, counters, xbuf, h0buf, h1buf);
  }
}

// Round 2
// 4818.291 us; speedup vs baseline: 3.3472x; 3.3472x over previous
//
#include <hip/hip_runtime.h>
#include <hip/hip_bf16.h>

#define T_STEPS 256
#define BATCH   64
#define HID     512
#define NWG     256   // 4 batch-groups x 64 unit-groups
#define NTHR    256   // 4 waves

typedef float f32x4 __attribute__((ext_vector_type(4)));
typedef short bf16x8 __attribute__((ext_vector_type(8)));

// LDS layout (dynamic shared, 148992 B total -> 1 WG/CU)
#define W0OFF   0u        // [32][1024] bf16, swizzled   (layer0)
#define W1OFF   65536u    // [32][1024] bf16, swizzled   (layer1)
#define WSTOFF  131072u   // [16][512] bf16, swizzled    (w_t rows; rows 8..15 zero)
#define T1OFF   147456u   // [16][16] f32 tile exchange (wave1 -> wave0)
#define BNCOFF  148480u   // [16][8]  f32 bounce (cell lanes -> row writers)
#define SMEM_BYTES 148992

__device__ __forceinline__ short f2b(float f) {
  __hip_bfloat16 h = __float2bfloat16(f);
  return *reinterpret_cast<short*>(&h);
}
__device__ __forceinline__ float b2f(short s) {
  __hip_bfloat16 h;
  *reinterpret_cast<short*>(&h) = s;
  return __bfloat162float(h);
}
__device__ __forceinline__ float sigf(float x) { return 1.0f / (1.0f + __expf(-x)); }
__device__ __forceinline__ float tanh_f(float x) { return 2.0f / (1.0f + __expf(-2.0f * x)) - 1.0f; }

__device__ __forceinline__ bf16x8 pack8(float4 a, float4 b) {
  bf16x8 r;
  r[0] = f2b(a.x); r[1] = f2b(a.y); r[2] = f2b(a.z); r[3] = f2b(a.w);
  r[4] = f2b(b.x); r[5] = f2b(b.y); r[6] = f2b(b.z); r[7] = f2b(b.w);
  return r;
}

// ---- cross-XCD communication: LLC-coherent (bypass L1+L2) loads/stores ----
__device__ __forceinline__ void llc_store16(void* p, bf16x8 v) {
  asm volatile("global_store_dwordx4 %0, %1, off sc0 sc1" :: "v"(p), "v"(v) : "memory");
}
// burst-load 8 x 16B from LLC at p + {0,64,...,448} bytes (NO waitcnt inside)
__device__ __forceinline__ void llc_load8x16(bf16x8* dst, const void* p) {
  asm volatile(
      "global_load_dwordx4 %0, %8, off sc0 sc1\n\t"
      "global_load_dwordx4 %1, %8, off offset:64 sc0 sc1\n\t"
      "global_load_dwordx4 %2, %8, off offset:128 sc0 sc1\n\t"
      "global_load_dwordx4 %3, %8, off offset:192 sc0 sc1\n\t"
      "global_load_dwordx4 %4, %8, off offset:256 sc0 sc1\n\t"
      "global_load_dwordx4 %5, %8, off offset:320 sc0 sc1\n\t"
      "global_load_dwordx4 %6, %8, off offset:384 sc0 sc1\n\t"
      "global_load_dwordx4 %7, %8, off offset:448 sc0 sc1"
      : "=v"(dst[0]), "=v"(dst[1]), "=v"(dst[2]), "=v"(dst[3]),
        "=v"(dst[4]), "=v"(dst[5]), "=v"(dst[6]), "=v"(dst[7])
      : "v"(p)
      : "memory");
}
__device__ __forceinline__ void wait_vm0(void) {
  asm volatile("s_waitcnt vmcnt(0)" ::: "memory");
  __builtin_amdgcn_sched_barrier(0);  // rule #18: keep reg-only MFMAs from hoisting
}

// poll a 32-slot counter group until every slot reaches 8 (256 WGs / 32 slots)
__device__ __forceinline__ void spin_group(unsigned int* g) {
  const int lane = threadIdx.x & 63;
  unsigned int* p = g + (lane & 31);
  for (;;) {
    unsigned int v = __hip_atomic_load(p, __ATOMIC_RELAXED, __HIP_MEMORY_SCOPE_AGENT);
    unsigned long long b = __ballot(v >= 8u);
    if ((b & 0xFFFFFFFFull) == 0xFFFFFFFFull) break;
    __builtin_amdgcn_s_sleep(1);
  }
}

// stage one layer's gate-row slice (32 rows x 1024 K) fp32 global -> bf16 LDS, XOR-swizzled
__device__ __forceinline__ void stage_weights(char* smem, unsigned int base,
                                              const float* Wih, const float* Whh,
                                              int u0, int tid) {
  for (int p = tid; p < 4096; p += NTHR) {
    const int row = p >> 7;            // 0..31  (0-7 i, 8-15 f, 16-23 g, 24-31 o)
    const int col = (p & 127) * 8;     // 0..1016
    const int gate = row >> 3;
    const int grow = gate * 512 + u0 + (row & 7);
    const float* src = (col < 512) ? (Wih + (size_t)grow * HID + col)
                                   : (Whh + (size_t)grow * HID + (col - 512));
    float4 v0 = *(const float4*)src;
    float4 v1 = *(const float4*)(src + 4);
    unsigned int byte = base + (unsigned int)row * 2048u + (unsigned int)col * 2u;
    byte ^= (unsigned int)(row & 7) << 4;
    *(bf16x8*)(smem + byte) = pack8(v0, v1);
  }
}

// gates[16 x 16-tile] = A[16,512](aA) @ W[:, :512]^T + A[16,512](aB) @ W[:, 512:]^T
// A-operands burst-loaded from LLC into registers; B from LDS (swizzled).
__device__ __forceinline__ f32x4 gates_mm(char* smem, const unsigned short* aA,
                                          const unsigned short* aB, unsigned int wOff,
                                          int tile, int bg, int lane) {
  const int arow = bg * 16 + (lane & 15);
  const int koff = (lane >> 4) * 8;
  bf16x8 ax[16], ah[16];
  const unsigned short* pa = aA + (size_t)arow * HID + koff;
  const unsigned short* pb = aB + (size_t)arow * HID + koff;
  llc_load8x16(ax, pa);
  llc_load8x16(ax + 8, pa + 256);
  llc_load8x16(ah, pb);
  llc_load8x16(ah + 8, pb + 256);
  wait_vm0();
  f32x4 acc = {0.f, 0.f, 0.f, 0.f};
  const int brow = tile * 16 + (lane & 15);
  const unsigned int bb = wOff + (unsigned int)brow * 2048u;
  const unsigned int sw = (unsigned int)(brow & 7) << 4;
#pragma unroll
  for (int ks = 0; ks < 16; ++ks) {
    bf16x8 b = *(const bf16x8*)(smem + ((bb + (unsigned int)((ks * 32 + koff) * 2)) ^ sw));
    acc = __builtin_amdgcn_mfma_f32_16x16x32_bf16(ax[ks], b, acc, 0, 0, 0);
  }
#pragma unroll
  for (int ks = 0; ks < 16; ++ks) {
    bf16x8 b = *(const bf16x8*)(smem + ((bb + (unsigned int)((512 + ks * 32 + koff) * 2)) ^ sw));
    acc = __builtin_amdgcn_mfma_f32_16x16x32_bf16(ah[ks], b, acc, 0, 0, 0);
  }
  return acc;
}

// wave0: acc = tile0 [i|f]; T1 in LDS = tile1 [g|o]; produces h (hv) and updates c (cst)
__device__ __forceinline__ void cell_update(char* smem, f32x4 acc, float bt0, float bgb,
                                            float bob, float* cst, float* hv, int lane) {
#pragma unroll
  for (int j = 0; j < 4; ++j) acc[j] += bt0;   // own-column bias (i or f)
  float part[4];
#pragma unroll
  for (int j = 0; j < 4; ++j) part[j] = __shfl_xor(acc[j], 8);
  const float* T1 = (const float*)(smem + T1OFF);
  const int cs = lane & 7;
  const int rb = (lane >> 4) * 4;
#pragma unroll
  for (int j = 0; j < 4; ++j) {
    const float iv = acc[j];                       // valid for lanes col<8
    const float fv = part[j];
    const float gv = T1[(rb + j) * 16 + cs] + bgb;
    const float ov = T1[(rb + j) * 16 + cs + 8] + bob;
    const float cn = sigf(fv) * cst[j] + sigf(iv) * tanh_f(gv);
    cst[j] = cn;
    hv[j] = sigf(ov) * tanh_f(cn);
  }
}

extern "C" __global__ void __launch_bounds__(NTHR, 1)
dlstm_kernel(const float* __restrict__ init_h, const float* __restrict__ init_c,
             const float* __restrict__ eps_w, const float* __restrict__ eps_b,
             const float* __restrict__ W_ih0, const float* __restrict__ W_hh0,
             const float* __restrict__ b_ih0, const float* __restrict__ b_hh0,
             const float* __restrict__ W_ih1, const float* __restrict__ W_hh1,
             const float* __restrict__ b_ih1, const float* __restrict__ b_hh1,
             const float* __restrict__ w_mu, const float* __restrict__ w_log_var,
             const float* __restrict__ b_mu, const float* __restrict__ b_log_var,
             float* __restrict__ out, unsigned int* __restrict__ counters,
             unsigned short* __restrict__ xbuf, unsigned short* __restrict__ h0buf,
             unsigned short* __restrict__ h1buf) {
  extern __shared__ char smem[];
  const int tid = threadIdx.x;
  const int bid = blockIdx.x;
  const int bg = bid & 3;            // batch group: rows [bg*16, bg*16+16)
  const int u0 = (bid >> 2) * 8;     // unit slice: [u0, u0+8) per layer
  const int wave = tid >> 6;
  const int lane = tid & 63;
  const int col = lane & 15;
  const int cs = lane & 7;
  const int rb = (lane >> 4) * 4;
  const int slot = bid >> 3;         // 32 counter slots, 8 WGs each
  const bool is_act = col < 8;
  const size_t BH = (size_t)BATCH * HID;

  // ---------------- one-time init ----------------
  stage_weights(smem, W0OFF, W_ih0, W_hh0, u0, tid);
  stage_weights(smem, W1OFF, W_ih1, W_hh1, u0, tid);
  {  // zero wstage pad rows 8..15 (MFMA N-tile is 16 wide, only 8 real rows)
    bf16x8 z = {0, 0, 0, 0, 0, 0, 0, 0};
    for (int p = tid; p < 512; p += NTHR) {
      const int row = 8 + (p >> 6);
      const int c8 = (p & 63) * 8;
      unsigned int byte = WSTOFF + (unsigned int)row * 1024u + (unsigned int)c8 * 2u;
      byte ^= (unsigned int)(row & 7) << 4;
      *(bf16x8*)(smem + byte) = z;
    }
  }
  // per-thread BL slice: row erow of w_t slice, 16 cols at ecb
  const int erow = tid >> 5;
  const int ecb = (tid & 31) * 16;
  float mu_r[16], sg_r[16], ewr[16];
  {
    const float* pm = w_mu + (size_t)(u0 + erow) * HID + ecb;
    const float* pv = w_log_var + (size_t)(u0 + erow) * HID + ecb;
#pragma unroll
    for (int q = 0; q < 16; ++q) { mu_r[q] = pm[q]; sg_r[q] = __expf(0.5f * pv[q]); }
    const float* pe = eps_w + (size_t)(u0 + erow) * HID + ecb;  // t = 0
#pragma unroll
    for (int q = 0; q < 16; ++q) ewr[q] = pe[q];
  }
  // wave0 per-lane constants + states
  float bt0_l0 = 0, bt0_l1 = 0, bgb0 = 0, bob0 = 0, bgb1 = 0, bob1 = 0, bmu_l = 0, bsg_l = 0;
  float c0r[4] = {0, 0, 0, 0}, c1r[4] = {0, 0, 0, 0};
  if (wave == 0) {
    const int ofs = (col < 8) ? 0 : 512;
    const int un = u0 + cs;
    bt0_l0 = b_ih0[ofs + un] + b_hh0[ofs + un];
    bt0_l1 = b_ih1[ofs + un] + b_hh1[ofs + un];
    bgb0 = b_ih0[1024 + un] + b_hh0[1024 + un];
    bob0 = b_ih0[1536 + un] + b_hh0[1536 + un];
    bgb1 = b_ih1[1024 + un] + b_hh1[1024 + un];
    bob1 = b_ih1[1536 + un] + b_hh1[1536 + un];
    bmu_l = b_mu[un];
    bsg_l = __expf(0.5f * b_log_var[un]);
    if (is_act) {
#pragma unroll
      for (int j = 0; j < 4; ++j) {
        c0r[j] = init_c[(size_t)(0 * BATCH + bg * 16 + rb + j) * HID + un];
        c1r[j] = init_c[(size_t)(1 * BATCH + bg * 16 + rb + j) * HID + un];
      }
    }
    if (lane < 16) {  // write this WG's tile of the parity-0 state buffers (LLC-coherent)
      const int row = bg * 16 + lane;
      const float* s0 = init_h + (size_t)row * HID + u0;
      const float* s1 = init_h + (size_t)(BATCH + row) * HID + u0;
      llc_store16(h0buf + (size_t)row * HID + u0,
                  pack8(*(const float4*)s0, *(const float4*)(s0 + 4)));
      llc_store16(h1buf + (size_t)row * HID + u0,
                  pack8(*(const float4*)s1, *(const float4*)(s1 + 4)));
      bf16x8 z = {0, 0, 0, 0, 0, 0, 0, 0};
      llc_store16(xbuf + (size_t)row * HID + u0, z);  // x_0 = 0
    }
  }
  __syncthreads();
  if (wave == 0) {
    asm volatile("s_waitcnt vmcnt(0)" ::: "memory");
    if (lane == 0)
      __hip_atomic_fetch_add(counters + slot, 1u, __ATOMIC_RELAXED, __HIP_MEMORY_SCOPE_AGENT);
  }

  // ---------------- time loop ----------------
#pragma unroll 1
  for (int t = 0; t < T_STEPS; ++t) {
    const int pp = t & 1;

    // build w_t slice into LDS (independent of recurrence; eps prefetched last iter)
    {
      bf16x8 v0, v1;
#pragma unroll
      for (int q = 0; q < 8; ++q) v0[q] = f2b(fmaf(sg_r[q], ewr[q], mu_r[q]));
#pragma unroll
      for (int q = 0; q < 8; ++q) v1[q] = f2b(fmaf(sg_r[q + 8], ewr[q + 8], mu_r[q + 8]));
      const unsigned int b0 = WSTOFF + (unsigned int)erow * 1024u + (unsigned int)ecb * 2u;
      const unsigned int sw = (unsigned int)(erow & 7) << 4;
      *(bf16x8*)(smem + (b0 ^ sw)) = v0;
      *(bf16x8*)(smem + ((b0 + 16u) ^ sw)) = v1;
    }
    if (t + 1 < T_STEPS) {  // prefetch eps_w[t+1] (plain cached loads)
      const float* pe = eps_w + (size_t)(t + 1) * HID * HID + (size_t)(u0 + erow) * HID + ecb;
#pragma unroll
      for (int q = 0; q < 16; ++q) ewr[q] = pe[q];
    }

    // ============== PHASE 0: gates0 -> h0 ==============
    if (wave == 0) spin_group(counters + 32 * (3 * t));  // t==0 -> init group
    __syncthreads();
    f32x4 acc = {0.f, 0.f, 0.f, 0.f};
    if (wave < 2) {
      acc = gates_mm(smem, xbuf + pp * BH, h0buf + pp * BH, W0OFF, wave, bg, lane);
      if (wave == 1) {
        float* T1 = (float*)(smem + T1OFF);
#pragma unroll
        for (int j = 0; j < 4; ++j) T1[(rb + j) * 16 + col] = acc[j];
      }
    }
    __syncthreads();
    if (wave == 0) {
      float hv[4];
      cell_update(smem, acc, bt0_l0, bgb0, bob0, c0r, hv, lane);
      float* BNC = (float*)(smem + BNCOFF);
      if (is_act) {
#pragma unroll
        for (int j = 0; j < 4; ++j) BNC[(rb + j) * 8 + cs] = hv[j];
      }
      asm volatile("s_waitcnt lgkmcnt(0)" ::: "memory");
      if (lane < 16) {
        const int row = bg * 16 + lane;
        float4 v0 = *(float4*)(BNC + lane * 8);
        float4 v1 = *(float4*)(BNC + lane * 8 + 4);
        llc_store16(h0buf + (size_t)(pp ^ 1) * BH + (size_t)row * HID + u0, pack8(v0, v1));
      }
      asm volatile("s_waitcnt vmcnt(0)" ::: "memory");
      if (lane == 0)
        __hip_atomic_fetch_add(counters + 32 * (1 + 3 * t) + slot, 1u, __ATOMIC_RELAXED,
                               __HIP_MEMORY_SCOPE_AGENT);
    }

    // ============== PHASE 1: gates1 -> h1 (+ d_out) ==============
    float ebv = 0.0f;
    if (wave == 0 && is_act) ebv = eps_b[(size_t)t * HID + u0 + cs];
    if (wave == 0) spin_group(counters + 32 * (1 + 3 * t));
    __syncthreads();
    if (wave < 2) {
      acc = gates_mm(smem, h0buf + (size_t)(pp ^ 1) * BH, h1buf + (size_t)pp * 2 * BH, W1OFF,
                     wave, bg, lane);
      if (wave == 1) {
        float* T1 = (float*)(smem + T1OFF);
#pragma unroll
        for (int j = 0; j < 4; ++j) T1[(rb + j) * 16 + col] = acc[j];
      }
    }
    __syncthreads();
    if (wave == 0) {
      float hv[4];
      cell_update(smem, acc, bt0_l1, bgb1, bob1, c1r, hv, lane);
      float* BNC = (float*)(smem + BNCOFF);
      if (is_act) {
#pragma unroll
        for (int j = 0; j < 4; ++j) BNC[(rb + j) * 8 + cs] = hv[j];
      }
      asm volatile("s_waitcnt lgkmcnt(0)" ::: "memory");
      if (lane < 16) {
        const int row = bg * 16 + lane;
        float4 v0 = *(float4*)(BNC + lane * 8);
        float4 v1 = *(float4*)(BNC + lane * 8 + 4);
        bf16x8 hi = pack8(v0, v1);
        unsigned short* base = h1buf + (size_t)(pp ^ 1) * 2 * BH;
        llc_store16(base + (size_t)row * HID + u0, hi);
        bf16x8 lo;  // residual for the BL matmul (w_t row norms ~5.4 amplify h1 error)
        const float* va = (const float*)&v0;
        const float* vb = (const float*)&v1;
#pragma unroll
        for (int q = 0; q < 8; ++q) {
          const float f = (q < 4) ? va[q] : vb[q - 4];
          lo[q] = f2b(f - b2f(hi[q]));
        }
        llc_store16(base + BH + (size_t)row * HID + u0, lo);
        float* od = out + ((size_t)t * BATCH + row) * HID + u0;
        *(float4*)od = v0;
        *(float4*)(od + 4) = v1;
      }
      asm volatile("s_waitcnt vmcnt(0)" ::: "memory");
      if (lane == 0)
        __hip_atomic_fetch_add(counters + 32 * (2 + 3 * t) + slot, 1u, __ATOMIC_RELAXED,
                               __HIP_MEMORY_SCOPE_AGENT);
    }

    // ============== PHASE 2: x_{t+1} = h1 @ w_t^T + b_t ==============
    if (t + 1 < T_STEPS) {
      if (wave == 0) spin_group(counters + 32 * (2 + 3 * t));
      __syncthreads();
      if (wave == 0) {
        const unsigned short* hh = h1buf + (size_t)(pp ^ 1) * 2 * BH;
        const int arow = bg * 16 + col;
        const int koff = (lane >> 4) * 8;
        bf16x8 ahi[16], alo[16];
        const unsigned short* ph = hh + (size_t)arow * HID + koff;
        const unsigned short* pl = hh + BH + (size_t)arow * HID + koff;
        llc_load8x16(ahi, ph);
        llc_load8x16(ahi + 8, ph + 256);
        llc_load8x16(alo, pl);
        llc_load8x16(alo + 8, pl + 256);
        wait_vm0();
        f32x4 a2 = {0.f, 0.f, 0.f, 0.f};
        const unsigned int bb = WSTOFF + (unsigned int)col * 1024u;
        const unsigned int sw = (unsigned int)(col & 7) << 4;
#pragma unroll
        for (int ks = 0; ks < 16; ++ks) {
          bf16x8 b = *(const bf16x8*)(smem + ((bb + (unsigned int)((ks * 32 + koff) * 2)) ^ sw));
          a2 = __builtin_amdgcn_mfma_f32_16x16x32_bf16(ahi[ks], b, a2, 0, 0, 0);
        }
#pragma unroll
        for (int ks = 0; ks < 16; ++ks) {
          bf16x8 b = *(const bf16x8*)(smem + ((bb + (unsigned int)((ks * 32 + koff) * 2)) ^ sw));
          a2 = __builtin_amdgcn_mfma_f32_16x16x32_bf16(alo[ks], b, a2, 0, 0, 0);
        }
        const float xb = bmu_l + bsg_l * ebv;
        float* BNC = (float*)(smem + BNCOFF);
        if (is_act) {
#pragma unroll
          for (int j = 0; j < 4; ++j) BNC[(rb + j) * 8 + cs] = a2[j] + xb;
        }
        asm volatile("s_waitcnt lgkmcnt(0)" ::: "memory");
        if (lane < 16) {
          const int row = bg * 16 + lane;
          float4 v0 = *(float4*)(BNC + lane * 8);
          float4 v1 = *(float4*)(BNC + lane * 8 + 4);
          llc_store16(xbuf + (size_t)(pp ^ 1) * BH + (size_t)row * HID + u0, pack8(v0, v1));
        }
        asm volatile("s_waitcnt vmcnt(0)" ::: "memory");
        if (lane == 0)
          __hip_atomic_fetch_add(counters + 32 * (3 + 3 * t) + slot, 1u, __ATOMIC_RELAXED,
                                 __HIP_MEMORY_SCOPE_AGENT);
      }
      __syncthreads();  // protect wstage rebuild at next loop top
    }
  }
}

extern "C" void kernel_launch(void* const* d_in, const int* in_sizes, int n_in, void* d_out,
                              int out_size, void* d_ws, size_t ws_size, hipStream_t stream) {
  const float* init_h = (const float*)d_in[1];
  const float* init_c = (const float*)d_in[2];
  const float* eps_w = (const float*)d_in[3];
  const float* eps_b = (const float*)d_in[4];
  const float* W_ih0 = (const float*)d_in[5];
  const float* W_hh0 = (const float*)d_in[6];
  const float* b_ih0 = (const float*)d_in[7];
  const float* b_hh0 = (const float*)d_in[8];
  const float* W_ih1 = (const float*)d_in[9];
  const float* W_hh1 = (const float*)d_in[10];
  const float* b_ih1 = (const float*)d_in[11];
  const float* b_hh1 = (const float*)d_in[12];
  const float* w_mu = (const float*)d_in[13];
  const float* w_log_var = (const float*)d_in[14];
  const float* b_mu = (const float*)d_in[15];
  const float* b_log_var = (const float*)d_in[16];
  float* out = (float*)d_out;

  unsigned char* ws = (unsigned char*)d_ws;
  unsigned int* counters = (unsigned int*)ws;                       // 769 groups * 32 * 4B
  unsigned short* xbuf = (unsigned short*)(ws + 131072);            // 2 parity * 64*512 bf16
  unsigned short* h0buf = (unsigned short*)(ws + 262144);           // 2 parity
  unsigned short* h1buf = (unsigned short*)(ws + 393216);           // 2 parity * {hi,lo}

  hipMemsetAsync(counters, 0, (1 + 3 * T_STEPS) * 32 * sizeof(unsigned int), stream);
  hipFuncSetAttribute((const void*)dlstm_kernel, hipFuncAttributeMaxDynamicSharedMemorySize,
                      SMEM_BYTES);

  void* args[] = {(void*)&init_h, (void*)&init_c, (void*)&eps_w,  (void*)&eps_b,
                  (void*)&W_ih0,  (void*)&W_hh0,  (void*)&b_ih0,  (void*)&b_hh0,
                  (void*)&W_ih1,  (void*)&W_hh1,  (void*)&b_ih1,  (void*)&b_hh1,
                  (void*)&w_mu,   (void*)&w_log_var, (void*)&b_mu, (void*)&b_log_var,
                  (void*)&out,    (void*)&counters,  (void*)&xbuf, (void*)&h0buf,
                  (void*)&h1buf};
  hipError_t err = hipLaunchCooperativeKernel((void*)dlstm_kernel, dim3(NWG), dim3(NTHR), args,
                                              SMEM_BYTES, stream);
  if (err != hipSuccess) {
    // fallback: plain launch (256 WGs at 1/CU on 256 CUs are co-resident by capacity)
    hipLaunchKernelGGL(dlstm_kernel, dim3(NWG), dim3(NTHR), SMEM_BYTES, stream, init_h, init_c,
                       eps_w, eps_b, W_ih0, W_hh0, b_ih0, b_hh0, W_ih1, W_hh1, b_ih1, b_hh1,
                       w_mu, w_log_var, b_mu, b_log_var, out, counters, xbuf, h0buf, h1buf);
  }
}